// Round 1
// baseline (56.719 us; speedup 1.0000x reference)
//
#include <hip/hip_runtime.h>
#include <math.h>

#define HALF_PI   1.57079632679489662f
#define INV_SQRT2 0.70710678118654752f

// ---------------------------------------------------------------------------
// K0: build the constant observable table from quantum_params [4,3].
// ctab[i]   = cos(theta_i)                (Z coefficient)
// ctab[4+i] = sin(theta_i) * cos(phi_i)   (X coefficient)
// omega is dropped: RZ(omega) is diagonal and cannot affect |amp|^2 of Z-basis
// measurements.
// ---------------------------------------------------------------------------
__global__ void setup_ctab(const float* __restrict__ qp, float* __restrict__ ctab) {
    if (threadIdx.x == 0 && blockIdx.x == 0) {
        #pragma unroll
        for (int i = 0; i < 4; ++i) {
            float phi = qp[3 * i + 0];
            float th  = qp[3 * i + 1];
            float sth, cth;
            sincosf(th, &sth, &cth);
            ctab[i]     = cth;
            ctab[4 + i] = sth * cosf(phi);
        }
    }
}

// ---------------------------------------------------------------------------
// K1: per-node projections. One wave (64 lanes) per node; lane l holds
// feat[node][4l..4l+3] as float4. 8 dot products (Wq rows 0..3, Wk rows 0..3),
// butterfly reduce, lane 0 applies tanh * pi/2 and writes float4 q/k.
// ---------------------------------------------------------------------------
__global__ __launch_bounds__(256) void node_qk(
        const float* __restrict__ feat,
        const float* __restrict__ Wq, const float* __restrict__ bq,
        const float* __restrict__ Wk, const float* __restrict__ bk,
        float4* __restrict__ qtab, float4* __restrict__ ktab, int N) {
    int gwave = (int)((blockIdx.x * blockDim.x + threadIdx.x) >> 6);
    int lane  = threadIdx.x & 63;
    if (gwave >= N) return;

    float4 f = reinterpret_cast<const float4*>(feat)[(size_t)gwave * 64 + lane];

    float acc[8];
    #pragma unroll
    for (int j = 0; j < 4; ++j) {
        float4 w = reinterpret_cast<const float4*>(Wq + j * 256)[lane];
        acc[j] = f.x * w.x + f.y * w.y + f.z * w.z + f.w * w.w;
    }
    #pragma unroll
    for (int j = 0; j < 4; ++j) {
        float4 w = reinterpret_cast<const float4*>(Wk + j * 256)[lane];
        acc[4 + j] = f.x * w.x + f.y * w.y + f.z * w.z + f.w * w.w;
    }

    #pragma unroll
    for (int off = 32; off > 0; off >>= 1) {
        #pragma unroll
        for (int j = 0; j < 8; ++j) acc[j] += __shfl_xor(acc[j], off, 64);
    }

    if (lane == 0) {
        float4 qv, kv;
        qv.x = tanhf(acc[0] + bq[0]) * HALF_PI;
        qv.y = tanhf(acc[1] + bq[1]) * HALF_PI;
        qv.z = tanhf(acc[2] + bq[2]) * HALF_PI;
        qv.w = tanhf(acc[3] + bq[3]) * HALF_PI;
        kv.x = tanhf(acc[4] + bk[0]) * HALF_PI;
        kv.y = tanhf(acc[5] + bk[1]) * HALF_PI;
        kv.z = tanhf(acc[6] + bk[2]) * HALF_PI;
        kv.w = tanhf(acc[7] + bk[3]) * HALF_PI;
        qtab[gwave] = qv;
        ktab[gwave] = kv;
    }
}

// ---------------------------------------------------------------------------
// K2: per-edge circuit. Real 16-amplitude simulation:
//   amps = product state from H*RY(q_w)|0> ; then 4 real CRY(k_w) rotations.
// attn = 0.25 * sum_i [ cz_i * <Z_i> - cx_i * 2*sum_pairs a0*a1 ]
// Writes exp(attn) to d_out and a deterministic per-block partial sum.
// ---------------------------------------------------------------------------
__global__ __launch_bounds__(256) void edge_attn(
        const int* __restrict__ ei,
        const float4* __restrict__ qtab, const float4* __restrict__ ktab,
        const float* __restrict__ ctab,
        float* __restrict__ exq, float* __restrict__ partial, int E) {
    int e = blockIdx.x * 256 + threadIdx.x;
    float ex = 0.f;
    if (e < E) {
        int src = ei[e];
        int dst = ei[E + e];
        float4 qv = qtab[src];
        float4 kv = ktab[dst];
        float qa[4] = {qv.x, qv.y, qv.z, qv.w};
        float ka[4] = {kv.x, kv.y, kv.z, kv.w};

        // u_w = H * RY(q_w) |0>  (real single-qubit states)
        float u[4][2];
        #pragma unroll
        for (int w = 0; w < 4; ++w) {
            float s, c;
            __sincosf(qa[w] * 0.5f, &s, &c);
            u[w][0] = (c + s) * INV_SQRT2;
            u[w][1] = (c - s) * INV_SQRT2;
        }

        // product state, wire 0 = most significant bit
        float a[16];
        #pragma unroll
        for (int x = 0; x < 16; ++x)
            a[x] = u[0][(x >> 3) & 1] * u[1][(x >> 2) & 1] *
                   u[2][(x >> 1) & 1] * u[3][x & 1];

        // CRY(k_w) control w, target (w+1)%4, applied in order w=0..3
        #pragma unroll
        for (int w = 0; w < 4; ++w) {
            float si, co;
            __sincosf(ka[w] * 0.5f, &si, &co);
            int cb = 1 << (3 - w);
            int tb = 1 << (3 - ((w + 1) & 3));
            #pragma unroll
            for (int x = 0; x < 16; ++x) {
                if ((x & cb) && !(x & tb)) {
                    float a0 = a[x], a1 = a[x | tb];
                    a[x]      = co * a0 - si * a1;
                    a[x | tb] = si * a0 + co * a1;
                }
            }
        }

        float p[16];
        #pragma unroll
        for (int x = 0; x < 16; ++x) p[x] = a[x] * a[x];

        float attn = 0.f;
        #pragma unroll
        for (int i = 0; i < 4; ++i) {
            int bit = 1 << (3 - i);
            float sz = 0.f, sx = 0.f;
            #pragma unroll
            for (int x = 0; x < 16; ++x) {
                sz += (x & bit) ? -p[x] : p[x];
                if (!(x & bit)) sx += a[x] * a[x | bit];
            }
            attn += ctab[i] * sz - ctab[4 + i] * (2.f * sx);
        }
        ex = __expf(attn * 0.25f);
    }

    // deterministic block-level partial sum
    __shared__ float red[256];
    red[threadIdx.x] = ex;
    __syncthreads();
    #pragma unroll
    for (int s = 128; s > 0; s >>= 1) {
        if (threadIdx.x < s) red[threadIdx.x] += red[threadIdx.x + s];
        __syncthreads();
    }
    if (threadIdx.x == 0) partial[blockIdx.x] = red[0];
    if (e < E) exq[e] = ex;
}

// ---------------------------------------------------------------------------
// K3: single-block deterministic reduction of block partials -> 1/sum
// ---------------------------------------------------------------------------
__global__ __launch_bounds__(256) void reduce_partials(
        const float* __restrict__ partial, int n, float* __restrict__ inv_out) {
    __shared__ float red[256];
    float s = 0.f;
    for (int i = threadIdx.x; i < n; i += 256) s += partial[i];
    red[threadIdx.x] = s;
    __syncthreads();
    #pragma unroll
    for (int st = 128; st > 0; st >>= 1) {
        if (threadIdx.x < st) red[threadIdx.x] += red[threadIdx.x + st];
        __syncthreads();
    }
    if (threadIdx.x == 0) inv_out[0] = 1.f / red[0];
}

// ---------------------------------------------------------------------------
// K4: normalize in place: out[e] *= inv_sum
// ---------------------------------------------------------------------------
__global__ __launch_bounds__(256) void normalize_out(
        float* __restrict__ out, const float* __restrict__ inv, int E) {
    int e = blockIdx.x * 256 + threadIdx.x;
    if (e < E) out[e] *= inv[0];
}

extern "C" void kernel_launch(void* const* d_in, const int* in_sizes, int n_in,
                              void* d_out, int out_size, void* d_ws, size_t ws_size,
                              hipStream_t stream) {
    const float* feat = (const float*)d_in[0];
    const int*   ei   = (const int*)d_in[1];
    const float* Wq   = (const float*)d_in[2];
    const float* bq   = (const float*)d_in[3];
    const float* Wk   = (const float*)d_in[4];
    const float* bk   = (const float*)d_in[5];
    const float* qp   = (const float*)d_in[6];

    int D = in_sizes[2] / 4;          // 256
    int N = in_sizes[0] / D;          // 50000
    int E = in_sizes[1] / 2;          // 800000
    (void)D;

    float* ws      = (float*)d_ws;
    float* ctab    = ws;              // 16 floats
    float* inv     = ws + 16;         // 16 floats
    float* partial = ws + 32;         // npart floats
    int npart = (E + 255) / 256;
    size_t qoff = 32 + (size_t)((npart + 15) & ~15);
    float4* qtab = (float4*)(ws + qoff);
    float4* ktab = qtab + N;

    float* out = (float*)d_out;

    setup_ctab<<<1, 64, 0, stream>>>(qp, ctab);
    node_qk<<<(N + 3) / 4, 256, 0, stream>>>(feat, Wq, bq, Wk, bk, qtab, ktab, N);
    edge_attn<<<npart, 256, 0, stream>>>(ei, qtab, ktab, ctab, out, partial, E);
    reduce_partials<<<1, 256, 0, stream>>>(partial, npart, inv);
    normalize_out<<<(E + 255) / 256, 256, 0, stream>>>(out, inv, E);
}

// Round 3
// 50.063 us; speedup vs baseline: 1.1329x; 1.1329x over previous
//
#include <hip/hip_runtime.h>
#include <math.h>

#define HALF_PI   1.57079632679489662f
#define INV_SQRT2 0.70710678118654752f
#define NPART     1024   // edge-kernel blocks / partial count

// ---------------------------------------------------------------------------
// K1: node projections. One node per wave per iteration, grid-stride.
// Lane l holds feat[n][4l..4l+3] and weight fragments Wq/Wk[q][4l..4l+3]
// preloaded in VGPRs (loaded ONCE per thread, amortized over ~12 nodes).
// Butterfly xor-reduce leaves every lane with all 8 dot products; lanes 0-7
// apply bias+tanh and store scalar.
// ---------------------------------------------------------------------------
__global__ __launch_bounds__(256) void node_qk(
        const float* __restrict__ feat,
        const float* __restrict__ Wq, const float* __restrict__ bq,
        const float* __restrict__ Wk, const float* __restrict__ bk,
        float* __restrict__ qtab, float* __restrict__ ktab, int N) {
    const int lane  = threadIdx.x & 63;
    const int wid   = (int)((blockIdx.x * blockDim.x + threadIdx.x) >> 6);
    const int nwid  = (int)((gridDim.x * blockDim.x) >> 6);

    // preload weight fragments (32 VGPRs)
    float4 wq4[4], wk4[4];
    #pragma unroll
    for (int q = 0; q < 4; ++q) {
        wq4[q] = reinterpret_cast<const float4*>(Wq + q * 256)[lane];
        wk4[q] = reinterpret_cast<const float4*>(Wk + q * 256)[lane];
    }
    const float bias = (lane < 4) ? bq[lane] : ((lane < 8) ? bk[lane - 4] : 0.f);

    for (int n = wid; n < N; n += nwid) {
        float4 f = reinterpret_cast<const float4*>(feat)[(size_t)n * 64 + lane];
        float acc[8];
        #pragma unroll
        for (int q = 0; q < 4; ++q) {
            acc[q]     = f.x * wq4[q].x + f.y * wq4[q].y + f.z * wq4[q].z + f.w * wq4[q].w;
            acc[4 + q] = f.x * wk4[q].x + f.y * wk4[q].y + f.z * wk4[q].z + f.w * wk4[q].w;
        }
        #pragma unroll
        for (int off = 32; off > 0; off >>= 1) {
            #pragma unroll
            for (int q = 0; q < 8; ++q) acc[q] += __shfl_xor(acc[q], off, 64);
        }
        if (lane < 8) {
            float v = tanhf(acc[lane] + bias) * HALF_PI;
            if (lane < 4) qtab[(size_t)n * 4 + lane] = v;
            else          ktab[(size_t)n * 4 + (lane - 4)] = v;
        }
    }
}

// ---------------------------------------------------------------------------
// K2: per-edge 4-qubit real simulation. ctab computed per block in LDS.
// Writes ex = exp(attn/4) to out and a deterministic per-block partial sum.
// Fixed grid of NPART blocks, grid-stride (EPT = 4 covers E <= 1048576).
// ---------------------------------------------------------------------------
__global__ __launch_bounds__(256) void edge_attn(
        const int* __restrict__ ei,
        const float4* __restrict__ qtab, const float4* __restrict__ ktab,
        const float* __restrict__ qp,
        float* __restrict__ out, float* __restrict__ partial, int E) {
    __shared__ float scz[4], scx[4];
    __shared__ float red[256];
    const int tid = threadIdx.x;
    if (tid < 4) {
        float phi = qp[3 * tid + 0];
        float th  = qp[3 * tid + 1];
        float sth, cth;
        sincosf(th, &sth, &cth);
        scz[tid] = cth;
        scx[tid] = sth * cosf(phi);
    }
    __syncthreads();

    const int total = NPART * 256;
    float lsum = 0.f;
    #pragma unroll
    for (int i = 0; i < 4; ++i) {
        const int e = blockIdx.x * 256 + tid + i * total;
        if (e < E) {
            const int src = ei[e];
            const int dst = ei[E + e];
            float4 qv = qtab[src];
            float4 kv = ktab[dst];
            float qa[4] = {qv.x, qv.y, qv.z, qv.w};
            float ka[4] = {kv.x, kv.y, kv.z, kv.w};

            // u_w = H * RY(q_w)|0>  (real)
            float u[4][2];
            #pragma unroll
            for (int w = 0; w < 4; ++w) {
                float s, c;
                __sincosf(qa[w] * 0.5f, &s, &c);
                u[w][0] = (c + s) * INV_SQRT2;
                u[w][1] = (c - s) * INV_SQRT2;
            }

            // 16-amplitude real product state, wire 0 = MSB
            float a[16];
            #pragma unroll
            for (int x = 0; x < 16; ++x)
                a[x] = u[0][(x >> 3) & 1] * u[1][(x >> 2) & 1] *
                       u[2][(x >> 1) & 1] * u[3][x & 1];

            // CRY(k_w) on (w, (w+1)%4)
            #pragma unroll
            for (int w = 0; w < 4; ++w) {
                float si, co;
                __sincosf(ka[w] * 0.5f, &si, &co);
                const int cb = 1 << (3 - w);
                const int tb = 1 << (3 - ((w + 1) & 3));
                #pragma unroll
                for (int x = 0; x < 16; ++x) {
                    if ((x & cb) && !(x & tb)) {
                        float a0 = a[x], a1 = a[x | tb];
                        a[x]      = co * a0 - si * a1;
                        a[x | tb] = si * a0 + co * a1;
                    }
                }
            }

            float attn = 0.f;
            #pragma unroll
            for (int q = 0; q < 4; ++q) {
                const int bit = 1 << (3 - q);
                float sz = 0.f, sx = 0.f;
                #pragma unroll
                for (int x = 0; x < 16; ++x) {
                    float pp = a[x] * a[x];
                    sz += (x & bit) ? -pp : pp;
                    if (!(x & bit)) sx += a[x] * a[x | bit];
                }
                attn += scz[q] * sz - scx[q] * (2.f * sx);
            }
            float ex = __expf(attn * 0.25f);
            out[e] = ex;
            lsum += ex;
        }
    }

    red[tid] = lsum;
    __syncthreads();
    #pragma unroll
    for (int s = 128; s > 0; s >>= 1) {
        if (tid < s) red[tid] += red[tid + s];
        __syncthreads();
    }
    if (tid == 0) partial[blockIdx.x] = red[0];
}

// ---------------------------------------------------------------------------
// K3: every block redundantly tree-reduces the NPART partials in identical
// order (same float result in all blocks), then normalizes its slice.
// ---------------------------------------------------------------------------
__global__ __launch_bounds__(256) void normalize_out(
        float* __restrict__ out, const float* __restrict__ partial, int E) {
    __shared__ float red[256];
    const int tid = threadIdx.x;
    float s = 0.f;
    #pragma unroll
    for (int k = 0; k < NPART / 256; ++k) s += partial[tid + k * 256];
    red[tid] = s;
    __syncthreads();
    #pragma unroll
    for (int st = 128; st > 0; st >>= 1) {
        if (tid < st) red[tid] += red[tid + st];
        __syncthreads();
    }
    const float inv = 1.f / red[0];

    const int total = (int)(gridDim.x * 256);
    for (int e = blockIdx.x * 256 + tid; e < E; e += total)
        out[e] *= inv;
}

extern "C" void kernel_launch(void* const* d_in, const int* in_sizes, int n_in,
                              void* d_out, int out_size, void* d_ws, size_t ws_size,
                              hipStream_t stream) {
    const float* feat = (const float*)d_in[0];
    const int*   ei   = (const int*)d_in[1];
    const float* Wq   = (const float*)d_in[2];
    const float* bq   = (const float*)d_in[3];
    const float* Wk   = (const float*)d_in[4];
    const float* bk   = (const float*)d_in[5];
    const float* qp   = (const float*)d_in[6];

    int D = in_sizes[2] / 4;          // 256
    int N = in_sizes[0] / D;          // 50000
    int E = in_sizes[1] / 2;          // 800000
    (void)D;

    float* ws      = (float*)d_ws;
    float* partial = ws;                         // NPART floats (4 KB)
    float* qtab    = ws + NPART;                 // 4N floats
    float* ktab    = qtab + (size_t)N * 4;       // 4N floats
    float* out     = (float*)d_out;

    node_qk<<<2048, 256, 0, stream>>>(feat, Wq, bq, Wk, bk, qtab, ktab, N);
    edge_attn<<<NPART, 256, 0, stream>>>(ei, (const float4*)qtab, (const float4*)ktab,
                                         qp, out, partial, E);
    normalize_out<<<1024, 256, 0, stream>>>(out, partial, E);
}

// Round 4
// 34.273 us; speedup vs baseline: 1.6549x; 1.4607x over previous
//
#include <hip/hip_runtime.h>
#include <math.h>

#define HALF_PI   1.57079632679489662f
#define INV_SQRT2 0.70710678118654752f
#define NPART     1024   // edge-kernel blocks / partial count

// ---------------------------------------------------------------------------
// K1: node projections. One node per wave per iteration, grid-stride.
// Lane l holds feat[n][4l..4l+3]; weight fragments (8 rows x 4 dims = 32
// VGPRs) preloaded once. Reduction: multi-value butterfly — rounds xor
// 32/16/8 exchange 4/2/1 DIFFERENT registers (values per lane halve), then
// 3 scalar rounds xor 4/2/1. 10 shuffles/node vs 48 naive. After the
// reduce, lane l holds dot[lane>>3] fully summed; group leaders write.
// All acc indices are compile-time constants (selects on lane bits) so
// nothing spills to scratch.
// ---------------------------------------------------------------------------
__global__ __launch_bounds__(256) void node_qk(
        const float* __restrict__ feat,
        const float* __restrict__ Wq, const float* __restrict__ bq,
        const float* __restrict__ Wk, const float* __restrict__ bk,
        float* __restrict__ qtab, float* __restrict__ ktab, int N) {
    const int lane  = threadIdx.x & 63;
    const int wid   = (int)((blockIdx.x * blockDim.x + threadIdx.x) >> 6);
    const int nwid  = (int)((gridDim.x * blockDim.x) >> 6);

    // preload weight fragments (32 VGPRs)
    float4 wq4[4], wk4[4];
    #pragma unroll
    for (int q = 0; q < 4; ++q) {
        wq4[q] = reinterpret_cast<const float4*>(Wq + q * 256)[lane];
        wk4[q] = reinterpret_cast<const float4*>(Wk + q * 256)[lane];
    }
    const int  g    = lane >> 3;                       // output index 0..7
    const float bias = (g < 4) ? bq[g] : bk[g & 3];

    const bool hi  = (lane & 32) != 0;
    const bool s16 = (lane & 16) != 0;
    const bool s8  = (lane & 8)  != 0;

    for (int n = wid; n < N; n += nwid) {
        float4 f = reinterpret_cast<const float4*>(feat)[(size_t)n * 64 + lane];
        float acc[8];
        #pragma unroll
        for (int q = 0; q < 4; ++q) {
            acc[q]     = f.x * wq4[q].x + f.y * wq4[q].y + f.z * wq4[q].z + f.w * wq4[q].w;
            acc[4 + q] = f.x * wk4[q].x + f.y * wk4[q].y + f.z * wk4[q].z + f.w * wk4[q].w;
        }

        // round 1 (xor 32): low lanes keep acc[0..3], high keep acc[4..7]
        #pragma unroll
        for (int j = 0; j < 4; ++j) {
            float give = hi ? acc[j] : acc[j + 4];
            float r = __shfl_xor(give, 32, 64);
            acc[j]     += hi ? 0.f : r;
            acc[j + 4] += hi ? r : 0.f;
        }
        // round 2 (xor 16): within each half, sub-low keeps first 2 live regs
        #pragma unroll
        for (int j = 0; j < 2; ++j) {
            float giveLow  = hi ? acc[6 + j] : acc[2 + j];  // sub-low gives these
            float giveHigh = hi ? acc[4 + j] : acc[j];      // sub-high gives these
            float give = s16 ? giveHigh : giveLow;
            float r = __shfl_xor(give, 16, 64);
            acc[j]     += (!hi && !s16) ? r : 0.f;
            acc[2 + j] += (!hi &&  s16) ? r : 0.f;
            acc[4 + j] += ( hi && !s16) ? r : 0.f;
            acc[6 + j] += ( hi &&  s16) ? r : 0.f;
        }
        // round 3 (xor 8): one live value remains; no writeback needed
        float a_even = hi ? (s16 ? acc[6] : acc[4]) : (s16 ? acc[2] : acc[0]);
        float a_odd  = hi ? (s16 ? acc[7] : acc[5]) : (s16 ? acc[3] : acc[1]);
        float give3 = s8 ? a_even : a_odd;
        float r3 = __shfl_xor(give3, 8, 64);
        float v = (s8 ? a_odd : a_even) + r3;
        // rounds 4-6: scalar butterfly over low 3 lane bits
        v += __shfl_xor(v, 4, 64);
        v += __shfl_xor(v, 2, 64);
        v += __shfl_xor(v, 1, 64);
        // every lane now holds dot[g], g = lane>>3

        if ((lane & 7) == 0) {
            float t = tanhf(v + bias) * HALF_PI;
            if (g < 4) qtab[(size_t)n * 4 + g] = t;
            else       ktab[(size_t)n * 4 + (g & 3)] = t;
        }
    }
}

// ---------------------------------------------------------------------------
// K2: per-edge 4-qubit real simulation. ctab computed per block in LDS.
// Writes ex = exp(attn/4) to out and a deterministic per-block partial sum.
// Fixed grid of NPART blocks (EPT = 4 covers E <= 1048576).
// ---------------------------------------------------------------------------
__global__ __launch_bounds__(256) void edge_attn(
        const int* __restrict__ ei,
        const float4* __restrict__ qtab, const float4* __restrict__ ktab,
        const float* __restrict__ qp,
        float* __restrict__ out, float* __restrict__ partial, int E) {
    __shared__ float scz[4], scx[4];
    __shared__ float red[256];
    const int tid = threadIdx.x;
    if (tid < 4) {
        float phi = qp[3 * tid + 0];
        float th  = qp[3 * tid + 1];
        float sth, cth;
        sincosf(th, &sth, &cth);
        scz[tid] = cth;
        scx[tid] = sth * cosf(phi);
    }
    __syncthreads();

    const int total = NPART * 256;
    float lsum = 0.f;
    #pragma unroll
    for (int i = 0; i < 4; ++i) {
        const int e = blockIdx.x * 256 + tid + i * total;
        if (e < E) {
            const int src = ei[e];
            const int dst = ei[E + e];
            float4 qv = qtab[src];
            float4 kv = ktab[dst];
            float qa[4] = {qv.x, qv.y, qv.z, qv.w};
            float ka[4] = {kv.x, kv.y, kv.z, kv.w};

            // u_w = H * RY(q_w)|0>  (real)
            float u[4][2];
            #pragma unroll
            for (int w = 0; w < 4; ++w) {
                float s, c;
                __sincosf(qa[w] * 0.5f, &s, &c);
                u[w][0] = (c + s) * INV_SQRT2;
                u[w][1] = (c - s) * INV_SQRT2;
            }

            // 16-amplitude real product state, wire 0 = MSB
            float a[16];
            #pragma unroll
            for (int x = 0; x < 16; ++x)
                a[x] = u[0][(x >> 3) & 1] * u[1][(x >> 2) & 1] *
                       u[2][(x >> 1) & 1] * u[3][x & 1];

            // CRY(k_w) on (w, (w+1)%4)
            #pragma unroll
            for (int w = 0; w < 4; ++w) {
                float si, co;
                __sincosf(ka[w] * 0.5f, &si, &co);
                const int cb = 1 << (3 - w);
                const int tb = 1 << (3 - ((w + 1) & 3));
                #pragma unroll
                for (int x = 0; x < 16; ++x) {
                    if ((x & cb) && !(x & tb)) {
                        float a0 = a[x], a1 = a[x | tb];
                        a[x]      = co * a0 - si * a1;
                        a[x | tb] = si * a0 + co * a1;
                    }
                }
            }

            float attn = 0.f;
            #pragma unroll
            for (int q = 0; q < 4; ++q) {
                const int bit = 1 << (3 - q);
                float sz = 0.f, sx = 0.f;
                #pragma unroll
                for (int x = 0; x < 16; ++x) {
                    float pp = a[x] * a[x];
                    sz += (x & bit) ? -pp : pp;
                    if (!(x & bit)) sx += a[x] * a[x | bit];
                }
                attn += scz[q] * sz - scx[q] * (2.f * sx);
            }
            float ex = __expf(attn * 0.25f);
            out[e] = ex;
            lsum += ex;
        }
    }

    red[tid] = lsum;
    __syncthreads();
    #pragma unroll
    for (int s = 128; s > 0; s >>= 1) {
        if (tid < s) red[tid] += red[tid + s];
        __syncthreads();
    }
    if (tid == 0) partial[blockIdx.x] = red[0];
}

// ---------------------------------------------------------------------------
// K3: every block redundantly tree-reduces the NPART partials in identical
// order (same float result in all blocks), then normalizes its slice.
// ---------------------------------------------------------------------------
__global__ __launch_bounds__(256) void normalize_out(
        float* __restrict__ out, const float* __restrict__ partial, int E) {
    __shared__ float red[256];
    const int tid = threadIdx.x;
    float s = 0.f;
    #pragma unroll
    for (int k = 0; k < NPART / 256; ++k) s += partial[tid + k * 256];
    red[tid] = s;
    __syncthreads();
    #pragma unroll
    for (int st = 128; st > 0; st >>= 1) {
        if (tid < st) red[tid] += red[tid + st];
        __syncthreads();
    }
    const float inv = 1.f / red[0];

    const int total = (int)(gridDim.x * 256);
    for (int e = blockIdx.x * 256 + tid; e < E; e += total)
        out[e] *= inv;
}

extern "C" void kernel_launch(void* const* d_in, const int* in_sizes, int n_in,
                              void* d_out, int out_size, void* d_ws, size_t ws_size,
                              hipStream_t stream) {
    const float* feat = (const float*)d_in[0];
    const int*   ei   = (const int*)d_in[1];
    const float* Wq   = (const float*)d_in[2];
    const float* bq   = (const float*)d_in[3];
    const float* Wk   = (const float*)d_in[4];
    const float* bk   = (const float*)d_in[5];
    const float* qp   = (const float*)d_in[6];

    int D = in_sizes[2] / 4;          // 256
    int N = in_sizes[0] / D;          // 50000
    int E = in_sizes[1] / 2;          // 800000
    (void)D;

    float* ws      = (float*)d_ws;
    float* partial = ws;                         // NPART floats (4 KB)
    float* qtab    = ws + NPART;                 // 4N floats
    float* ktab    = qtab + (size_t)N * 4;       // 4N floats
    float* out     = (float*)d_out;

    node_qk<<<2048, 256, 0, stream>>>(feat, Wq, bq, Wk, bk, qtab, ktab, N);
    edge_attn<<<NPART, 256, 0, stream>>>(ei, (const float4*)qtab, (const float4*)ktab,
                                         qp, out, partial, E);
    normalize_out<<<1024, 256, 0, stream>>>(out, partial, E);
}